// Round 2
// baseline (199.678 us; speedup 1.0000x reference)
//
#include <hip/hip_runtime.h>

// B=16384 bags, HIST=50, K=128, EMB_DIM=3. Three chained linears with no
// activation collapse into one 3x128 affine map (collapse_weights_kernel).
// Fused kernel: one 64-lane wave per bag; 4 lanes per embedding row
// (component c = lane&3, row selected by quad q = lane>>2) so the HW
// coalescer merges each quad's 3 component loads into ~1 line request.

#define KDIM 128

// --- Kernel 1: collapse the 3 linear layers into Wc[3][128], bc[3] ----------
__global__ __launch_bounds__(KDIM) void collapse_weights_kernel(
    const float* __restrict__ w0, const float* __restrict__ b0,
    const float* __restrict__ w1, const float* __restrict__ b1,
    const float* __restrict__ w2, const float* __restrict__ b2,
    float* __restrict__ ws) // ws[0..383] = Wc row-major, ws[384..386] = bc
{
    __shared__ float t[6][KDIM];   // w1 @ w0  (6 x 128)
    __shared__ float tb[6];        // w1 @ b0 + b1

    const int k = threadIdx.x;     // 0..127
    for (int i = 0; i < 6; ++i) {
        float acc = 0.f;
        for (int j = 0; j < 12; ++j)
            acc += w1[i * 12 + j] * w0[j * KDIM + k];
        t[i][k] = acc;
    }
    if (k < 6) {
        float acc = 0.f;
        for (int j = 0; j < 12; ++j)
            acc += w1[k * 12 + j] * b0[j];
        tb[k] = acc + b1[k];
    }
    __syncthreads();

    for (int o = 0; o < 3; ++o) {
        float acc = 0.f;
        for (int i = 0; i < 6; ++i)
            acc += w2[o * 6 + i] * t[i][k];
        ws[o * KDIM + k] = acc;
    }
    if (k == 0) {
        for (int o = 0; o < 3; ++o) {
            float acc = 0.f;
            for (int i = 0; i < 6; ++i)
                acc += w2[o * 6 + i] * tb[i];
            ws[3 * KDIM + o] = acc + b2[o];
        }
    }
}

// --- Kernel 2: fused embedding-bag mean + collapsed MLP ---------------------
// Lane layout: c = lane&3 (component, c==3 idle), q = lane>>2 (quad, 0..15).
// Gather: quad q handles rows q, q+16, q+32, ... — the quad's 3 active lanes
// read 3 consecutive dwords of one row -> 1 coalesced line request.
// MLP: lane (c,q) accumulates x[q*8 .. q*8+8) . Wc[c][q*8 .. q*8+8).
// Butterfly over xor-offsets {4,8,16,32} reduces across q while preserving c.
// Writer lanes (q<4, c<3): col = q*3 + c; q<3 -> embedding mean, q==3 -> MLP.
__global__ __launch_bounds__(256) void fused_embbag_mlp_kernel(
    const int* __restrict__ eb_input,     // [N] indices (int32)
    const int* __restrict__ eb_offset,    // [B] bag starts
    const float* __restrict__ mlp_input,  // [B, 128]
    const float* __restrict__ emb_weight, // [NUM_EMB, 3]
    const float* __restrict__ ws,         // Wc[3][128], bc[3]
    float* __restrict__ out,              // [B, 12]
    int n_indices, int num_bags)
{
    const int lane = threadIdx.x & 63;
    const int wave = threadIdx.x >> 6;
    const int bag  = blockIdx.x * (blockDim.x >> 6) + wave;
    if (bag >= num_bags) return;

    const int c = lane & 3;
    const int q = lane >> 2;

    const int start = eb_offset[bag];
    const int end   = (bag + 1 < num_bags) ? eb_offset[bag + 1] : n_indices;
    const int cnt   = end - start;

    float s = 0.f;   // embedding component partial
    float m = 0.f;   // MLP dot partial

    if (c < 3) {
        for (int row = q; row < cnt; row += 16) {
            const int idx = eb_input[start + row];
            s += emb_weight[(long long)idx * 3 + c];
        }
        // MLP: 8 elements per lane, two float4 loads each side
        const float4* xp = (const float4*)(mlp_input + (long long)bag * KDIM + q * 8);
        const float4* wp = (const float4*)(ws + c * KDIM + q * 8);
        const float4 x0 = xp[0], x1 = xp[1];
        const float4 wv0 = wp[0], wv1 = wp[1];
        m = x0.x * wv0.x + x0.y * wv0.y + x0.z * wv0.z + x0.w * wv0.w
          + x1.x * wv1.x + x1.y * wv1.y + x1.z * wv1.z + x1.w * wv1.w;
    }

    // Reduce across quads (offsets 4..32 preserve lane&3)
    #pragma unroll
    for (int off = 4; off <= 32; off <<= 1) {
        s += __shfl_xor(s, off, 64);
        m += __shfl_xor(m, off, 64);
    }

    if (c < 3 && q < 4) {
        const float inv = 1.0f / fmaxf((float)cnt, 1.0f);
        const int col = q * 3 + c;
        const float v = (q < 3) ? s * inv : (m + ws[3 * KDIM + c]);
        out[(long long)bag * 12 + col] = v;
    }
}

extern "C" void kernel_launch(void* const* d_in, const int* in_sizes, int n_in,
                              void* d_out, int out_size, void* d_ws, size_t ws_size,
                              hipStream_t stream) {
    const int*   eb_input   = (const int*)d_in[0];   // [B*HIST] int32
    const int*   eb_offset  = (const int*)d_in[1];   // [B] int32
    const float* mlp_input  = (const float*)d_in[2]; // [B,128]
    const float* emb_weight = (const float*)d_in[3]; // [10M,3]
    const float* w0 = (const float*)d_in[4];
    const float* b0 = (const float*)d_in[5];
    const float* w1 = (const float*)d_in[6];
    const float* b1 = (const float*)d_in[7];
    const float* w2 = (const float*)d_in[8];
    const float* b2 = (const float*)d_in[9];
    float* out = (float*)d_out;
    float* ws  = (float*)d_ws;   // 387 floats used

    const int n_indices = in_sizes[0];
    const int num_bags  = in_sizes[1];

    collapse_weights_kernel<<<1, KDIM, 0, stream>>>(w0, b0, w1, b1, w2, b2, ws);

    const int waves_per_block = 4;                 // 256 threads
    const int grid = (num_bags + waves_per_block - 1) / waves_per_block;
    fused_embbag_mlp_kernel<<<grid, 256, 0, stream>>>(
        eb_input, eb_offset, mlp_input, emb_weight, ws, out, n_indices, num_bags);
}

// Round 3
// 198.463 us; speedup vs baseline: 1.0061x; 1.0061x over previous
//
#include <hip/hip_runtime.h>

// B=16384 bags, HIST=50, K=128, EMB_DIM=3. Three chained linears with no
// activation collapse into one 3x128 affine map (collapse_weights_kernel).
// Fused kernel: one 64-lane wave per bag; lane layout c=lane&3 (component,
// c==3 idle), q=lane>>2 (row-quad). Gather is FULLY UNROLLED into 4
// predicated rounds so each lane keeps 4 independent HBM loads in flight
// (the loop version serialized on one outstanding miss per lane).

#define KDIM 128

// --- Kernel 1: collapse the 3 linear layers into Wc[3][128], bc[3] ----------
__global__ __launch_bounds__(KDIM) void collapse_weights_kernel(
    const float* __restrict__ w0, const float* __restrict__ b0,
    const float* __restrict__ w1, const float* __restrict__ b1,
    const float* __restrict__ w2, const float* __restrict__ b2,
    float* __restrict__ ws) // ws[0..383] = Wc row-major, ws[384..386] = bc
{
    __shared__ float t[6][KDIM];   // w1 @ w0  (6 x 128)
    __shared__ float tb[6];        // w1 @ b0 + b1

    const int k = threadIdx.x;     // 0..127
    for (int i = 0; i < 6; ++i) {
        float acc = 0.f;
        for (int j = 0; j < 12; ++j)
            acc += w1[i * 12 + j] * w0[j * KDIM + k];
        t[i][k] = acc;
    }
    if (k < 6) {
        float acc = 0.f;
        for (int j = 0; j < 12; ++j)
            acc += w1[k * 12 + j] * b0[j];
        tb[k] = acc + b1[k];
    }
    __syncthreads();

    for (int o = 0; o < 3; ++o) {
        float acc = 0.f;
        for (int i = 0; i < 6; ++i)
            acc += w2[o * 6 + i] * t[i][k];
        ws[o * KDIM + k] = acc;
    }
    if (k == 0) {
        for (int o = 0; o < 3; ++o) {
            float acc = 0.f;
            for (int i = 0; i < 6; ++i)
                acc += w2[o * 6 + i] * tb[i];
            ws[3 * KDIM + o] = acc + b2[o];
        }
    }
}

// --- Kernel 2: fused embedding-bag mean + collapsed MLP ---------------------
// Quad q handles rows q, q+16, q+32, q+48 (covers cnt<=64; rare tail loop
// beyond). All 4 index loads issue back-to-back, then all 4 row gathers —
// 4 outstanding misses per lane. Out-of-range rounds are address-clamped
// (load a valid row) and value-masked to 0.
__global__ __launch_bounds__(256) void fused_embbag_mlp_kernel(
    const int* __restrict__ eb_input,     // [N] indices (int32)
    const int* __restrict__ eb_offset,    // [B] bag starts
    const float* __restrict__ mlp_input,  // [B, 128]
    const float* __restrict__ emb_weight, // [NUM_EMB, 3]
    const float* __restrict__ ws,         // Wc[3][128], bc[3]
    float* __restrict__ out,              // [B, 12]
    int n_indices, int num_bags)
{
    const int lane = threadIdx.x & 63;
    const int wave = threadIdx.x >> 6;
    const int bag  = blockIdx.x * (blockDim.x >> 6) + wave;
    if (bag >= num_bags) return;

    const int c = lane & 3;
    const int q = lane >> 2;

    const int start = eb_offset[bag];
    const int end   = (bag + 1 < num_bags) ? eb_offset[bag + 1] : n_indices;
    const int cnt   = end - start;

    float s = 0.f;   // embedding component partial
    float m = 0.f;   // MLP dot partial

    if (c < 3 && cnt > 0) {
        const int last = end - 1;
        const int p0 = start + q, p1 = p0 + 16, p2 = p1 + 16, p3 = p2 + 16;
        // Address-clamped index loads (4 independent VMEM ops)
        const int j0 = min(p0, last), j1 = min(p1, last),
                  j2 = min(p2, last), j3 = min(p3, last);
        const int i0 = eb_input[j0];
        const int i1 = eb_input[j1];
        const int i2 = eb_input[j2];
        const int i3 = eb_input[j3];
        // 4 independent row gathers in flight
        const float g0 = emb_weight[(long long)i0 * 3 + c];
        const float g1 = emb_weight[(long long)i1 * 3 + c];
        const float g2 = emb_weight[(long long)i2 * 3 + c];
        const float g3 = emb_weight[(long long)i3 * 3 + c];
        s = (p0 < end ? g0 : 0.f) + (p1 < end ? g1 : 0.f)
          + (p2 < end ? g2 : 0.f) + (p3 < end ? g3 : 0.f);
        // Rare tail (cnt > 64) — never taken for HIST=50
        for (int r = start + 64 + q; r < end; r += 16)
            s += emb_weight[(long long)eb_input[r] * 3 + c];

        // MLP: 8 elements per lane, two float4 loads each side (independent
        // of the gathers; overlaps their latency)
        const float4* xp = (const float4*)(mlp_input + (long long)bag * KDIM + q * 8);
        const float4* wp = (const float4*)(ws + c * KDIM + q * 8);
        const float4 x0 = xp[0], x1 = xp[1];
        const float4 wv0 = wp[0], wv1 = wp[1];
        m = x0.x * wv0.x + x0.y * wv0.y + x0.z * wv0.z + x0.w * wv0.w
          + x1.x * wv1.x + x1.y * wv1.y + x1.z * wv1.z + x1.w * wv1.w;
    }

    // Reduce across quads (xor offsets 4..32 preserve lane&3)
    #pragma unroll
    for (int off = 4; off <= 32; off <<= 1) {
        s += __shfl_xor(s, off, 64);
        m += __shfl_xor(m, off, 64);
    }

    if (c < 3 && q < 4) {
        const float inv = 1.0f / fmaxf((float)cnt, 1.0f);
        const int col = q * 3 + c;
        const float v = (q < 3) ? s * inv : (m + ws[3 * KDIM + c]);
        out[(long long)bag * 12 + col] = v;
    }
}

extern "C" void kernel_launch(void* const* d_in, const int* in_sizes, int n_in,
                              void* d_out, int out_size, void* d_ws, size_t ws_size,
                              hipStream_t stream) {
    const int*   eb_input   = (const int*)d_in[0];   // [B*HIST] int32
    const int*   eb_offset  = (const int*)d_in[1];   // [B] int32
    const float* mlp_input  = (const float*)d_in[2]; // [B,128]
    const float* emb_weight = (const float*)d_in[3]; // [10M,3]
    const float* w0 = (const float*)d_in[4];
    const float* b0 = (const float*)d_in[5];
    const float* w1 = (const float*)d_in[6];
    const float* b1 = (const float*)d_in[7];
    const float* w2 = (const float*)d_in[8];
    const float* b2 = (const float*)d_in[9];
    float* out = (float*)d_out;
    float* ws  = (float*)d_ws;   // 387 floats used

    const int n_indices = in_sizes[0];
    const int num_bags  = in_sizes[1];

    collapse_weights_kernel<<<1, KDIM, 0, stream>>>(w0, b0, w1, b1, w2, b2, ws);

    const int waves_per_block = 4;                 // 256 threads
    const int grid = (num_bags + waves_per_block - 1) / waves_per_block;
    fused_embbag_mlp_kernel<<<grid, 256, 0, stream>>>(
        eb_input, eb_offset, mlp_input, emb_weight, ws, out, n_indices, num_bags);
}